// Round 9
// baseline (111.089 us; speedup 1.0000x reference)
//
#include <hip/hip_runtime.h>
#include <math.h>

// Problem constants: N=8, S=8192, C=1, K=1024, V=64
#define NS   65536
#define KK   1024
#define VV   64
#define SPB  256              // samples per block (4 waves x 64)
#define NB   (NS / SPB)       // 256 blocks -> exactly 1 block/CU
#define CHC  256              // codes per LDS chunk (32 KB)
#define NCHK (KK / CHC)       // 4 chunks
#define TPC  (CHC / 16)       // 16 MFMA tiles per chunk
#define CHB  (CHC * VV * 2)   // chunk bytes (32768)

// Output layout (flat, return order):
#define OUT0_OFF 0            // (8,8192,1,64) = 4,194,304
#define OUT1_OFF 4194304
#define OUT2_OFF 4259840
#define ENT_OFF  4325376      // entropy scalar; doubles as completion counter

// ws layout: [0,4K) hist u32; [4K,8K) cinit f32 (=1-0.5|e|^2); [8K,136K) swizzled bf16 codebook

typedef __attribute__((ext_vector_type(8))) short bf16x8;
typedef __attribute__((ext_vector_type(4))) float f32x4;

// async global->LDS 16B DMA: LDS dst = wave-uniform base + lane*16
#define ASYNC16(gp, lp) __builtin_amdgcn_global_load_lds(                      \
    (const __attribute__((address_space(1))) unsigned int*)(gp),               \
    (__attribute__((address_space(3))) unsigned int*)(lp), 16, 0, 0)

__device__ __forceinline__ short f2bf(float f) {
    unsigned u = __float_as_uint(f);
    u = (u + 0x7fffu + ((u >> 16) & 1u)) >> 16;   // RNE
    return (short)u;
}

__global__ void vq_prep(const float* __restrict__ emb, unsigned int* __restrict__ hist,
                        float* __restrict__ cinit, short* __restrict__ cb,
                        unsigned int* __restrict__ entCnt) {
    int t = blockIdx.x * blockDim.x + threadIdx.x;   // 1024 threads, one code each
    if (t == 0) entCnt[0] = 0u;
    if (t < KK) {
        hist[t] = 0u;
        const float4* e4 = (const float4*)(emb + (size_t)t * VV);
        const int ch = t >> 8, cw = t & 255;
        short* base = cb + (size_t)ch * (CHC * VV) + cw * 64;   // code block (8 granules)
        float s = 0.f;
        union { short sh[8]; bf16x8 v; } pk;
        #pragma unroll
        for (int g = 0; g < 8; ++g) {
            float4 f0 = e4[2 * g], f1 = e4[2 * g + 1];
            s = fmaf(f0.x, f0.x, s); s = fmaf(f0.y, f0.y, s);
            s = fmaf(f0.z, f0.z, s); s = fmaf(f0.w, f0.w, s);
            s = fmaf(f1.x, f1.x, s); s = fmaf(f1.y, f1.y, s);
            s = fmaf(f1.z, f1.z, s); s = fmaf(f1.w, f1.w, s);
            pk.sh[0] = f2bf(f0.x); pk.sh[1] = f2bf(f0.y);
            pk.sh[2] = f2bf(f0.z); pk.sh[3] = f2bf(f0.w);
            pk.sh[4] = f2bf(f1.x); pk.sh[5] = f2bf(f1.y);
            pk.sh[6] = f2bf(f1.z); pk.sh[7] = f2bf(f1.w);
            // swizzled granule slot: g ^ (cw&7)  -> LDS-linear staging lands conflict-free
            *(bf16x8*)(base + ((g ^ (cw & 7)) * 8)) = pk.v;
        }
        cinit[t] = 1.0f - 0.5f * s;   // MFMA C-init; keeps scores in (0.85,1.15)
    }
}

__global__ __launch_bounds__(256, 1) void vq_main(
    const float* __restrict__ x, const float* __restrict__ emb,
    const float* __restrict__ cinit, const short* __restrict__ cb,
    unsigned int* __restrict__ hist,
    float* __restrict__ out0, float* __restrict__ out1, float* __restrict__ out2,
    float* __restrict__ entOut)
{
    __shared__ __align__(16) char  sCB[2][CHB];   // 2 x 32 KB, swizzled chunks
    __shared__ __align__(16) float sCI[KK];       // 4 KB
    __shared__ unsigned sPk[SPB];
    __shared__ float    sXn[SPB];
    __shared__ float    sPart[4];
    __shared__ unsigned sLast;
    __shared__ char     sPad[12288];   // bump LDS ~82 KB: forces exactly 1 block/CU

    const int tid  = threadIdx.x;
    const int lane = tid & 63;
    const int wv   = tid >> 6;
    const int col  = lane & 15;     // code-within-tile / A-row m
    const int quad = lane >> 4;     // k-granule group
    const int samp0 = blockIdx.x * SPB;
    const int wbase = wv * 64;      // wave's 64 samples within block

    sPad[tid] = (char)tid;          // keep the pad array alive

    // ---- kick off async staging of chunk 0 (no VGPR round-trip) ----
    {
        const char* g0 = (const char*)cb;
        #pragma unroll
        for (int i = 0; i < 8; ++i) {
            const int off = (i * 256 + tid) * 16;
            ASYNC16(g0 + off, sCB[0] + off);
        }
        ((float4*)sCI)[tid] = ((const float4*)cinit)[tid];
    }

    // ---- A fragments (4 m-tiles) + fp32 |x|^2 per sample (covers staging latency) ----
    bf16x8 a[8];
    float  xn[4];
    #pragma unroll
    for (int mt = 0; mt < 4; ++mt) {
        const float* xp = x + (size_t)(samp0 + wbase + mt * 16 + col) * VV + quad * 8;
        float4 p0 = *(const float4*)(xp);
        float4 p1 = *(const float4*)(xp + 4);
        float4 p2 = *(const float4*)(xp + 32);
        float4 p3 = *(const float4*)(xp + 36);
        bf16x8 lo, hi;
        lo[0]=f2bf(p0.x); lo[1]=f2bf(p0.y); lo[2]=f2bf(p0.z); lo[3]=f2bf(p0.w);
        lo[4]=f2bf(p1.x); lo[5]=f2bf(p1.y); lo[6]=f2bf(p1.z); lo[7]=f2bf(p1.w);
        hi[0]=f2bf(p2.x); hi[1]=f2bf(p2.y); hi[2]=f2bf(p2.z); hi[3]=f2bf(p2.w);
        hi[4]=f2bf(p3.x); hi[5]=f2bf(p3.y); hi[6]=f2bf(p3.z); hi[7]=f2bf(p3.w);
        a[2 * mt] = lo; a[2 * mt + 1] = hi;
        float s = 0.f;
        s=fmaf(p0.x,p0.x,s); s=fmaf(p0.y,p0.y,s); s=fmaf(p0.z,p0.z,s); s=fmaf(p0.w,p0.w,s);
        s=fmaf(p1.x,p1.x,s); s=fmaf(p1.y,p1.y,s); s=fmaf(p1.z,p1.z,s); s=fmaf(p1.w,p1.w,s);
        s=fmaf(p2.x,p2.x,s); s=fmaf(p2.y,p2.y,s); s=fmaf(p2.z,p2.z,s); s=fmaf(p2.w,p2.w,s);
        s=fmaf(p3.x,p3.x,s); s=fmaf(p3.y,p3.y,s); s=fmaf(p3.z,p3.z,s); s=fmaf(p3.w,p3.w,s);
        xn[mt] = s;
    }
    #pragma unroll
    for (int mt = 0; mt < 4; ++mt) {     // reduce |x|^2 over the 4 k-quads
        xn[mt] += __shfl_xor(xn[mt], 16, 64);
        xn[mt] += __shfl_xor(xn[mt], 32, 64);
    }
    __syncthreads();   // chunk-0 DMA + sCI visible (latency covered by A-frag work)

    // packed running maxima: high 22 bits = score (positive fp32), low 10 = 1023-code
    unsigned pm[16];
    #pragma unroll
    for (int j = 0; j < 16; ++j) pm[j] = 0u;

    const int rb0off = col * 128 + ((quad ^ (col & 7)) << 4);
    const int rb1off = col * 128 + (((4 + quad) ^ (col & 7)) << 4);
    const unsigned invc = 1023u - (unsigned)col;

    for (int ch = 0; ch < NCHK; ++ch) {
        if (ch + 1 < NCHK) {            // async prefetch next chunk (in flight ~1 chunk)
            const char* g = (const char*)cb + (size_t)(ch + 1) * CHB;
            char* nb = sCB[(ch + 1) & 1];
            #pragma unroll
            for (int i = 0; i < 8; ++i) {
                const int off = (i * 256 + tid) * 16;
                ASYNC16(g + off, nb + off);
            }
        }
        const char* B = sCB[ch & 1];
        const unsigned invch = invc - (unsigned)(ch * CHC);
        unsigned pkp[16];
        #pragma unroll
        for (int tl = 0; tl < TPC; ++tl) {
            bf16x8 b0 = *(const bf16x8*)(B + tl * 2048 + rb0off);
            bf16x8 b1 = *(const bf16x8*)(B + tl * 2048 + rb1off);
            float ci = sCI[ch * CHC + tl * 16 + col];
            f32x4 cv = {ci, ci, ci, ci};
            const unsigned inv = invch - (unsigned)(tl * 16);
            unsigned pk2[16];
            #pragma unroll
            for (int mt = 0; mt < 4; ++mt) {
                f32x4 acc = __builtin_amdgcn_mfma_f32_16x16x32_bf16(a[2*mt],     b0, cv,  0, 0, 0);
                acc       = __builtin_amdgcn_mfma_f32_16x16x32_bf16(a[2*mt + 1], b1, acc, 0, 0, 0);
                #pragma unroll
                for (int r = 0; r < 4; ++r)
                    pk2[mt*4+r] = (__float_as_uint(acc[r]) & 0xFFFFFC00u) | inv;  // v_and_or_b32
            }
            if (tl & 1) {
                #pragma unroll
                for (int j = 0; j < 16; ++j) {      // v_max3_u32
                    unsigned t2 = pkp[j] > pk2[j] ? pkp[j] : pk2[j];
                    pm[j] = pm[j] > t2 ? pm[j] : t2;
                }
            } else {
                #pragma unroll
                for (int j = 0; j < 16; ++j) pkp[j] = pk2[j];
            }
        }
        __syncthreads();   // buffer handoff (prefetch DMA drained; it landed under compute)
    }

    // ---- reduce packed maxima over the 16 cols of each quad group ----
    #pragma unroll
    for (int off = 1; off < 16; off <<= 1) {
        #pragma unroll
        for (int j = 0; j < 16; ++j) {
            unsigned o = (unsigned)__shfl_xor((int)pm[j], off, 64);
            pm[j] = (o > pm[j]) ? o : pm[j];
        }
    }
    if (col == 0) {
        #pragma unroll
        for (int mt = 0; mt < 4; ++mt)
            #pragma unroll
            for (int r = 0; r < 4; ++r)
                sPk[wbase + mt * 16 + quad * 4 + r] = pm[mt * 4 + r];  // D row = quad*4+r
    }
    if (quad == 0) {
        #pragma unroll
        for (int mt = 0; mt < 4; ++mt) sXn[wbase + mt * 16 + col] = xn[mt];
    }
    __syncthreads();

    // ---- epilogue: d^2 = |x|^2 - 2(score-1);  score = 1 + x.e - 0.5|e|^2 ----
    {
        unsigned p = sPk[tid];
        int   code = 1023 - (int)(p & 1023u);
        float sf   = __uint_as_float(p & 0xFFFFFC00u);
        float d    = fmaf(-2.f, sf - 1.0f, sXn[tid]);   // sf-1 exact (Sterbenz)
        int n = samp0 + tid;
        out1[n] = d;
        out2[n] = d;
        atomicAdd(&hist[code], 1u);
    }
    #pragma unroll
    for (int h = 0; h < 2; ++h) {   // coalesced out0: lane pair covers one 256B row
        const int smp  = h * 128 + (tid >> 1);
        const int half = tid & 1;
        const int code = 1023 - (int)(sPk[smp] & 1023u);
        const float4* src = (const float4*)(emb + (size_t)code * VV + half * 32);
        float4*       dst = (float4*)(out0 + (size_t)(samp0 + smp) * VV + half * 32);
        #pragma unroll
        for (int i = 0; i < 8; ++i) dst[i] = src[i];
    }

    // ---- completion counter + fused entropy in the last block ----
    __syncthreads();   // vmcnt(0) drain => this block's hist atomics globally visible
    unsigned int* entCnt = (unsigned int*)entOut;
    if (tid == 0) sLast = (atomicAdd(entCnt, 1u) == (NB - 1)) ? 1u : 0u;
    __syncthreads();
    if (sLast) {
        float e = 0.f;
        #pragma unroll
        for (int i = 0; i < 4; ++i) {
            unsigned c = atomicAdd(&hist[i * 256 + tid], 0u);   // coherent read
            if (c) { float p = (float)c * (1.0f / (float)NS); e -= p * logf(p); }
        }
        #pragma unroll
        for (int off = 32; off > 0; off >>= 1) e += __shfl_down(e, off, 64);
        if (lane == 0) sPart[wv] = e;
        __syncthreads();
        if (tid == 0) entOut[0] = sPart[0] + sPart[1] + sPart[2] + sPart[3];
    }
}

extern "C" void kernel_launch(void* const* d_in, const int* in_sizes, int n_in,
                              void* d_out, int out_size, void* d_ws, size_t ws_size,
                              hipStream_t stream) {
    const float* x   = (const float*)d_in[0];   // (8,8192,1,64) fp32
    const float* emb = (const float*)d_in[1];   // (1,1024,64) fp32
    float* out = (float*)d_out;
    unsigned int* hist  = (unsigned int*)d_ws;
    float*        cinit = (float*)((char*)d_ws + 4096);
    short*        cb    = (short*)((char*)d_ws + 8192);   // swizzled bf16 codebook, 128 KB

    vq_prep<<<4, 256, 0, stream>>>(emb, hist, cinit, cb, (unsigned int*)(out + ENT_OFF));
    vq_main<<<NB, 256, 0, stream>>>(x, emb, cinit, cb, hist,
                                    out + OUT0_OFF, out + OUT1_OFF, out + OUT2_OFF,
                                    out + ENT_OFF);
}

// Round 10
// 102.223 us; speedup vs baseline: 1.0867x; 1.0867x over previous
//
#include <hip/hip_runtime.h>
#include <math.h>

// Problem constants: N=8, S=8192, C=1, K=1024, V=64
#define NS   65536
#define KK   1024
#define VV   64
#define SPB  128              // samples per block (4 waves x 32)
#define NB   (NS / SPB)       // 512 blocks -> 2 blocks/CU (balanced), 8 waves/CU
#define CHC  256              // codes per LDS chunk (32 KB)
#define NCHK (KK / CHC)       // 4 chunks
#define TPC  (CHC / 16)       // 16 MFMA tiles per chunk
#define CHB  (CHC * VV * 2)   // chunk bytes (32768)
#define NREP 8                // codebook replicas (one per XCD via blockIdx&7)

// Output layout (flat, return order):
#define OUT0_OFF 0            // (8,8192,1,64) = 4,194,304
#define OUT1_OFF 4194304
#define OUT2_OFF 4259840
#define ENT_OFF  4325376      // entropy scalar; doubles as completion counter

// ws layout: [0,4K) hist u32; [4K,36K) cinit f32 x8 replicas;
//            [36K, 36K+8*128K) swizzled bf16 codebook x8 replicas
#define WS_CINIT 4096
#define WS_CB    36864

typedef __attribute__((ext_vector_type(8))) short bf16x8;
typedef __attribute__((ext_vector_type(4))) float f32x4;

// async global->LDS 16B DMA: LDS dst = wave-uniform base + lane*16
#define ASYNC16(gp, lp) __builtin_amdgcn_global_load_lds(                      \
    (const __attribute__((address_space(1))) unsigned int*)(gp),               \
    (__attribute__((address_space(3))) unsigned int*)(lp), 16, 0, 0)

__device__ __forceinline__ short f2bf(float f) {
    unsigned u = __float_as_uint(f);
    u = (u + 0x7fffu + ((u >> 16) & 1u)) >> 16;   // RNE
    return (short)u;
}

// 32 blocks x 256: block b handles replica p=b>>2, codes (b&3)*256 + tid
__global__ void vq_prep(const float* __restrict__ emb, unsigned int* __restrict__ hist,
                        float* __restrict__ cinit, short* __restrict__ cb,
                        unsigned int* __restrict__ entCnt) {
    const int p = blockIdx.x >> 2;                       // replica 0..7
    const int t = (blockIdx.x & 3) * 256 + threadIdx.x;  // code 0..1023
    if (p == 0) {
        if (t == 0) entCnt[0] = 0u;
        hist[t] = 0u;
    }
    const float4* e4 = (const float4*)(emb + (size_t)t * VV);
    const int ch = t >> 8, cw = t & 255;
    short* base = cb + (size_t)p * (KK * VV) + (size_t)ch * (CHC * VV) + cw * 64;
    float s = 0.f;
    union { short sh[8]; bf16x8 v; } pk;
    #pragma unroll
    for (int g = 0; g < 8; ++g) {
        float4 f0 = e4[2 * g], f1 = e4[2 * g + 1];
        s = fmaf(f0.x, f0.x, s); s = fmaf(f0.y, f0.y, s);
        s = fmaf(f0.z, f0.z, s); s = fmaf(f0.w, f0.w, s);
        s = fmaf(f1.x, f1.x, s); s = fmaf(f1.y, f1.y, s);
        s = fmaf(f1.z, f1.z, s); s = fmaf(f1.w, f1.w, s);
        pk.sh[0] = f2bf(f0.x); pk.sh[1] = f2bf(f0.y);
        pk.sh[2] = f2bf(f0.z); pk.sh[3] = f2bf(f0.w);
        pk.sh[4] = f2bf(f1.x); pk.sh[5] = f2bf(f1.y);
        pk.sh[6] = f2bf(f1.z); pk.sh[7] = f2bf(f1.w);
        // swizzled granule slot: g ^ (cw&7) -> LDS-linear staging lands conflict-free
        *(bf16x8*)(base + ((g ^ (cw & 7)) * 8)) = pk.v;
    }
    cinit[p * KK + t] = 1.0f - 0.5f * s;   // MFMA C-init; keeps scores in (0.85,1.15)
}

__global__ __launch_bounds__(256, 2) void vq_main(
    const float* __restrict__ x, const float* __restrict__ emb,
    const float* __restrict__ cinit, const short* __restrict__ cb,
    unsigned int* __restrict__ hist,
    float* __restrict__ out0, float* __restrict__ out1, float* __restrict__ out2,
    float* __restrict__ entOut)
{
    __shared__ __align__(16) char  sCB[2][CHB];   // 2 x 32 KB, swizzled chunks
    __shared__ __align__(16) float sCI[KK];       // 4 KB
    __shared__ unsigned sPk[SPB];
    __shared__ float    sXn[SPB];
    __shared__ float    sPart[4];
    __shared__ unsigned sLast;

    const int tid  = threadIdx.x;
    const int lane = tid & 63;
    const int wv   = tid >> 6;
    const int col  = lane & 15;     // code-within-tile / A-row m
    const int quad = lane >> 4;     // k-granule group
    const int samp0 = blockIdx.x * SPB;
    const int wbase = wv * 32;      // wave's 32 samples within block

    // replica selection: XCD round-robin heuristic (correct regardless of mapping)
    const short* cbp = cb    + (size_t)(blockIdx.x & (NREP - 1)) * (KK * VV);
    const float* cip = cinit + (blockIdx.x & (NREP - 1)) * KK;

    // ---- kick off async staging of chunk 0 (no VGPR round-trip) ----
    {
        const char* g0 = (const char*)cbp;
        #pragma unroll
        for (int i = 0; i < 8; ++i) {
            const int off = (i * 256 + tid) * 16;
            ASYNC16(g0 + off, sCB[0] + off);
        }
        ((float4*)sCI)[tid] = ((const float4*)cip)[tid];
    }

    // ---- A fragments (2 m-tiles) + fp32 |x|^2 per sample (covers staging latency) ----
    bf16x8 a[4];
    float  xn[2];
    #pragma unroll
    for (int mt = 0; mt < 2; ++mt) {
        const float* xp = x + (size_t)(samp0 + wbase + mt * 16 + col) * VV + quad * 8;
        float4 p0 = *(const float4*)(xp);
        float4 p1 = *(const float4*)(xp + 4);
        float4 p2 = *(const float4*)(xp + 32);
        float4 p3 = *(const float4*)(xp + 36);
        bf16x8 lo, hi;
        lo[0]=f2bf(p0.x); lo[1]=f2bf(p0.y); lo[2]=f2bf(p0.z); lo[3]=f2bf(p0.w);
        lo[4]=f2bf(p1.x); lo[5]=f2bf(p1.y); lo[6]=f2bf(p1.z); lo[7]=f2bf(p1.w);
        hi[0]=f2bf(p2.x); hi[1]=f2bf(p2.y); hi[2]=f2bf(p2.z); hi[3]=f2bf(p2.w);
        hi[4]=f2bf(p3.x); hi[5]=f2bf(p3.y); hi[6]=f2bf(p3.z); hi[7]=f2bf(p3.w);
        a[2 * mt] = lo; a[2 * mt + 1] = hi;
        float s = 0.f;
        s=fmaf(p0.x,p0.x,s); s=fmaf(p0.y,p0.y,s); s=fmaf(p0.z,p0.z,s); s=fmaf(p0.w,p0.w,s);
        s=fmaf(p1.x,p1.x,s); s=fmaf(p1.y,p1.y,s); s=fmaf(p1.z,p1.z,s); s=fmaf(p1.w,p1.w,s);
        s=fmaf(p2.x,p2.x,s); s=fmaf(p2.y,p2.y,s); s=fmaf(p2.z,p2.z,s); s=fmaf(p2.w,p2.w,s);
        s=fmaf(p3.x,p3.x,s); s=fmaf(p3.y,p3.y,s); s=fmaf(p3.z,p3.z,s); s=fmaf(p3.w,p3.w,s);
        xn[mt] = s;
    }
    #pragma unroll
    for (int mt = 0; mt < 2; ++mt) {     // reduce |x|^2 over the 4 k-quads
        xn[mt] += __shfl_xor(xn[mt], 16, 64);
        xn[mt] += __shfl_xor(xn[mt], 32, 64);
    }
    __syncthreads();   // chunk-0 DMA + sCI visible (latency covered by A-frag work)

    // packed running maxima: high 22 bits = score (positive fp32), low 10 = 1023-code
    unsigned pm[8];
    #pragma unroll
    for (int j = 0; j < 8; ++j) pm[j] = 0u;

    const int rb0off = col * 128 + ((quad ^ (col & 7)) << 4);
    const int rb1off = col * 128 + (((4 + quad) ^ (col & 7)) << 4);
    const unsigned invc = 1023u - (unsigned)col;

    for (int ch = 0; ch < NCHK; ++ch) {
        if (ch + 1 < NCHK) {            // async prefetch next chunk (in flight ~1 chunk)
            const char* g = (const char*)cbp + (size_t)(ch + 1) * CHB;
            char* nb = sCB[(ch + 1) & 1];
            #pragma unroll
            for (int i = 0; i < 8; ++i) {
                const int off = (i * 256 + tid) * 16;
                ASYNC16(g + off, nb + off);
            }
        }
        const char* B = sCB[ch & 1];
        const unsigned invch = invc - (unsigned)(ch * CHC);
        unsigned pkp[8];
        #pragma unroll
        for (int tl = 0; tl < TPC; ++tl) {
            bf16x8 b0 = *(const bf16x8*)(B + tl * 2048 + rb0off);
            bf16x8 b1 = *(const bf16x8*)(B + tl * 2048 + rb1off);
            float ci = sCI[ch * CHC + tl * 16 + col];
            f32x4 cv = {ci, ci, ci, ci};
            const unsigned inv = invch - (unsigned)(tl * 16);
            unsigned pk2[8];
            #pragma unroll
            for (int mt = 0; mt < 2; ++mt) {
                f32x4 acc = __builtin_amdgcn_mfma_f32_16x16x32_bf16(a[2*mt],     b0, cv,  0, 0, 0);
                acc       = __builtin_amdgcn_mfma_f32_16x16x32_bf16(a[2*mt + 1], b1, acc, 0, 0, 0);
                #pragma unroll
                for (int r = 0; r < 4; ++r)
                    pk2[mt*4+r] = (__float_as_uint(acc[r]) & 0xFFFFFC00u) | inv;  // v_and_or_b32
            }
            if (tl & 1) {
                #pragma unroll
                for (int j = 0; j < 8; ++j) {      // v_max3_u32
                    unsigned t2 = pkp[j] > pk2[j] ? pkp[j] : pk2[j];
                    pm[j] = pm[j] > t2 ? pm[j] : t2;
                }
            } else {
                #pragma unroll
                for (int j = 0; j < 8; ++j) pkp[j] = pk2[j];
            }
        }
        __syncthreads();   // buffer handoff (prefetch DMA landed under compute)
    }

    // ---- reduce packed maxima over the 16 cols of each quad group ----
    #pragma unroll
    for (int off = 1; off < 16; off <<= 1) {
        #pragma unroll
        for (int j = 0; j < 8; ++j) {
            unsigned o = (unsigned)__shfl_xor((int)pm[j], off, 64);
            pm[j] = (o > pm[j]) ? o : pm[j];
        }
    }
    if (col == 0) {
        #pragma unroll
        for (int mt = 0; mt < 2; ++mt)
            #pragma unroll
            for (int r = 0; r < 4; ++r)
                sPk[wbase + mt * 16 + quad * 4 + r] = pm[mt * 4 + r];  // D row = quad*4+r
    }
    if (quad == 0) {
        #pragma unroll
        for (int mt = 0; mt < 2; ++mt) sXn[wbase + mt * 16 + col] = xn[mt];
    }
    __syncthreads();

    // ---- epilogue: d^2 = |x|^2 - 2(score-1);  score = 1 + x.e - 0.5|e|^2 ----
    if (tid < SPB) {
        unsigned p = sPk[tid];
        int   code = 1023 - (int)(p & 1023u);
        float sf   = __uint_as_float(p & 0xFFFFFC00u);
        float d    = fmaf(-2.f, sf - 1.0f, sXn[tid]);   // sf-1 exact (Sterbenz)
        int n = samp0 + tid;
        out1[n] = d;
        out2[n] = d;
        atomicAdd(&hist[code], 1u);
    }
    // ---- out0 gather-write, R3-measured dense pattern: 64B contiguous per thread ----
    #pragma unroll
    for (int h = 0; h < 2; ++h) {
        const int smp = h * 64 + (tid >> 2);
        const int v0  = (tid & 3) * 16;
        const int code = 1023 - (int)(sPk[smp] & 1023u);
        const float4* src = (const float4*)(emb + (size_t)code * VV + v0);
        float4*       dst = (float4*)(out0 + (size_t)(samp0 + smp) * VV + v0);
        #pragma unroll
        for (int i = 0; i < 4; ++i) dst[i] = src[i];
    }

    // ---- completion counter + fused entropy in the last block ----
    __syncthreads();   // vmcnt(0) drain => this block's hist atomics globally visible
    unsigned int* entCnt = (unsigned int*)entOut;
    if (tid == 0) sLast = (atomicAdd(entCnt, 1u) == (NB - 1)) ? 1u : 0u;
    __syncthreads();
    if (sLast) {
        float e = 0.f;
        #pragma unroll
        for (int i = 0; i < 4; ++i) {
            unsigned c = atomicAdd(&hist[i * 256 + tid], 0u);   // coherent read
            if (c) { float p = (float)c * (1.0f / (float)NS); e -= p * logf(p); }
        }
        #pragma unroll
        for (int off = 32; off > 0; off >>= 1) e += __shfl_down(e, off, 64);
        if (lane == 0) sPart[wv] = e;
        __syncthreads();
        if (tid == 0) entOut[0] = sPart[0] + sPart[1] + sPart[2] + sPart[3];
    }
}

extern "C" void kernel_launch(void* const* d_in, const int* in_sizes, int n_in,
                              void* d_out, int out_size, void* d_ws, size_t ws_size,
                              hipStream_t stream) {
    const float* x   = (const float*)d_in[0];   // (8,8192,1,64) fp32
    const float* emb = (const float*)d_in[1];   // (1,1024,64) fp32
    float* out = (float*)d_out;
    unsigned int* hist  = (unsigned int*)d_ws;
    float*        cinit = (float*)((char*)d_ws + WS_CINIT);   // 8 replicas
    short*        cb    = (short*)((char*)d_ws + WS_CB);      // 8 swizzled replicas

    vq_prep<<<32, 256, 0, stream>>>(emb, hist, cinit, cb, (unsigned int*)(out + ENT_OFF));
    vq_main<<<NB, 256, 0, stream>>>(x, emb, cinit, cb, hist,
                                    out + OUT0_OFF, out + OUT1_OFF, out + OUT2_OFF,
                                    out + ENT_OFF);
}